// Round 12
// baseline (183.865 us; speedup 1.0000x reference)
//
#include <hip/hip_runtime.h>
#include <math.h>

#define NQ   12
#define NL   4
#define DIM  4096          // 2^NQ
#define BLK  256
#define APT  16            // amplitudes per thread

typedef float v2f __attribute__((ext_vector_type(2)));
typedef __fp16 h2 __attribute__((ext_vector_type(2)));   // matches cvt_pkrtz return

// LDS dword address of amplitude i (re/im packed f16x2 in one dword).
// XOR bank swizzle: dword bits 2..4 ^= (i>>5 ^ i>>9)&7. Keeps 16B groups
// (bits 0..1) intact for b128. GF(2)-linear for disjoint-bit arguments.
// Verified: W1/R1' (i=tid<<4|4k) -> 8 consecutive lanes cover all 32 banks
// (conflict-free); R2 (i=th<<8|r<<4|tl) and R3 (i=r<<8|tid) -> exactly 2-way
// (free on CDNA4, m136).
__device__ __forceinline__ constexpr int wmix(int i) {
    return i ^ ((((i >> 5) ^ (i >> 9)) & 7) << 2);
}

// Inverse CNOT-ring map (CNOTs are involutions; apply in forward order) — for
// the sigma-folded scatter: store pre[i] at slot sigma_inv(i).
__device__ __forceinline__ constexpr int sigma_inv_c(int i) {
    int j = i;
    for (int c = 0; c < NQ; ++c) {
        int t = (c + 1) % NQ;
        int cb = (j >> (NQ - 1 - c)) & 1;
        j ^= cb << (NQ - 1 - t);
    }
    return j;
}

// fp32x2 <-> packed fp16x2 (1 VALU pack via v_cvt_pkrtz, 2 cvt unpack).
__device__ __forceinline__ unsigned pkamp(v2f a) {
    h2 h = __builtin_amdgcn_cvt_pkrtz(a.x, a.y);
    return __builtin_bit_cast(unsigned, h);
}
__device__ __forceinline__ v2f unpkamp(unsigned u) {
    h2 h = __builtin_bit_cast(h2, u);
    return (v2f){ (float)h.x, (float)h.y };
}

// Packed-complex gate update: N0 = u00*A0 + u01*A1, N1 = u10*A0 + u11*A1.
// Gate table stores real coeffs as {ur,ur} and imag coeffs as {-ui,+ui}, so
// the shuffled term is a PURE half-swap (no negate) -> folds to op_sel:[1,0].
#define CGATE(AV, R0, R1)                                            \
  { const v2f A0 = AV[R0], A1 = AV[R1];                              \
    const v2f A0s = __builtin_shufflevector(A0, A0, 1, 0);           \
    const v2f A1s = __builtin_shufflevector(A1, A1, 1, 0);           \
    v2f N0 = b00r * A0;                                              \
    N0 = __builtin_elementwise_fma(b00i, A0s, N0);                   \
    N0 = __builtin_elementwise_fma(b01r, A1,  N0);                   \
    N0 = __builtin_elementwise_fma(b01i, A1s, N0);                   \
    v2f N1 = b10r * A0;                                              \
    N1 = __builtin_elementwise_fma(b10i, A0s, N1);                   \
    N1 = __builtin_elementwise_fma(b11r, A1,  N1);                   \
    N1 = __builtin_elementwise_fma(b11i, A1s, N1);                   \
    AV[R0] = N0; AV[R1] = N1; }

// 4 gates on register-index bits 3..0; bit j <-> wire WB+3-j. Gate coeffs are
// wave-uniform global loads (scalar path).
#define APPLY4(LB, WB)                                               \
  { _Pragma("unroll")                                                \
    for (int j = 0; j < 4; ++j) {                                    \
      const int gb = ((LB) + (WB) + 3 - j) * 8;                      \
      const v2f b00r = gg[gb + 0], b00i = gg[gb + 1];                \
      const v2f b01r = gg[gb + 2], b01i = gg[gb + 3];                \
      const v2f b10r = gg[gb + 4], b10i = gg[gb + 5];                \
      const v2f b11r = gg[gb + 6], b11i = gg[gb + 7];                \
      _Pragma("unroll")                                              \
      for (int h = 0; h < 8; ++h) {                                  \
        const int r0 = ((h >> j) << (j + 1)) | (h & ((1 << j) - 1)); \
        CGATE(av, r0, r0 | (1 << j));                                \
      }                                                              \
    } }

// ---- pre-kernel: fuse RZ*RY*RX into d_ws ----
// Per gate 16 floats: entry k (u00,u01,u10,u11): [4k]={ur,ur}, [4k+2]={-ui,+ui}.
__global__ __launch_bounds__(64) void gate_kernel(
    const float* __restrict__ qw, float* __restrict__ gout)
{
    const int t = threadIdx.x;
    if (t < NL * NQ) {
        const int p = (t / NQ) * 3 * NQ + 3 * (t % NQ);
        float t1 = qw[p], t2 = qw[p + 1], t3 = qw[p + 2];
        float a, b, c, d, gr, h;
        sincosf(0.5f * t1, &b, &a);   // RX
        sincosf(0.5f * t2, &d, &c);   // RY
        sincosf(0.5f * t3, &h, &gr);  // RZ
        float m00r =  c * a, m00i =  d * b;
        float m01r = -d * a, m01i = -c * b;
        float m10r =  d * a, m10i = -c * b;
        float m11r =  c * a, m11i = -d * b;
        float G[8];
        G[0] = gr * m00r + h * m00i;  G[1] = gr * m00i - h * m00r;
        G[2] = gr * m01r + h * m01i;  G[3] = gr * m01i - h * m01r;
        G[4] = gr * m10r - h * m10i;  G[5] = gr * m10i + h * m10r;
        G[6] = gr * m11r - h * m11i;  G[7] = gr * m11i + h * m11r;
        #pragma unroll
        for (int k = 0; k < 4; ++k) {
            gout[t * 16 + 4 * k + 0] =  G[2 * k];
            gout[t * 16 + 4 * k + 1] =  G[2 * k];
            gout[t * 16 + 4 * k + 2] = -G[2 * k + 1];
            gout[t * 16 + 4 * k + 3] =  G[2 * k + 1];
        }
    }
}

__global__ __launch_bounds__(BLK) void qsim_kernel(
    const float* __restrict__ x,      // (B, 12)
    const float* __restrict__ gates,  // (48*16,) arranged gate matrices (d_ws)
    const float* __restrict__ dw,     // (12, 12)
    const float* __restrict__ db,     // (12,)
    float* __restrict__ out)          // (B, 12)
{
    // State as packed f16x2 per amp: 16384 B -> 8 blocks/CU (wave-cap bound).
    __shared__ __align__(16) unsigned sh[DIM];
    float* xv    = (float*)sh;        // aliases, dead once state staged
    float* enc_c = (float*)sh + 16;
    float* enc_s = (float*)sh + 32;
    float* red   = (float*)sh;        // reused after final barrier

    const int tid  = threadIdx.x;
    const int lane = tid & 63;
    const int wv   = tid >> 6;
    const int s    = blockIdx.x;
    const v2f* __restrict__ gg = (const v2f*)gates;

    if (tid < NQ) xv[tid] = x[s * NQ + tid];
    __syncthreads();
    if (tid < NQ) {
        float ss = 0.f;
        #pragma unroll
        for (int j = 0; j < NQ; ++j) ss += xv[j] * xv[j];
        float inv = rsqrtf(fmaxf(ss, 1e-12f));
        float mx = 0.f;
        #pragma unroll
        for (int j = 0; j < NQ; ++j) mx = fmaxf(mx, fabsf(xv[j] * inv));
        float ang = 3.14159265358979323846f * (xv[tid] * inv) / (mx + 1e-8f);
        float cc, sn;
        sincosf(0.5f * ang, &sn, &cc);
        enc_c[tid] = cc; enc_s[tid] = sn;
    }
    __syncthreads();

    // ---- product-state init in registers (O1: i = (tid<<4)|r) ----
    v2f av[APT];
    {
        float prefix = 1.f;
        #pragma unroll
        for (int w = 0; w < 8; ++w)
            prefix *= ((tid >> (7 - w)) & 1) ? enc_s[w] : enc_c[w];
        float u4[4], v4[4];
        #pragma unroll
        for (int k = 0; k < 4; ++k) {
            u4[k] = ((k & 2) ? enc_s[8]  : enc_c[8])  * ((k & 1) ? enc_s[9]  : enc_c[9]);
            v4[k] = ((k & 2) ? enc_s[10] : enc_c[10]) * ((k & 1) ? enc_s[11] : enc_c[11]);
        }
        #pragma unroll
        for (int r = 0; r < APT; ++r)
            av[r] = (v2f){ prefix * u4[r >> 2] * v4[r & 3], 0.f };
    }
    __syncthreads();   // enc reads done before W1 overwrites the alias region

    // Address bases (per-r offsets are compile-time XORs; maps GF(2)-linear).
    const int a1 = wmix(tid << 4);                           // O1 (W1, R1')
    const int a2 = wmix(((tid & 0xF0) << 4) | (tid & 0x0F)); // O2: i=th<<8|r<<4|tl
    const int a3 = wmix(tid);                                // O3: i=(r<<8)|tid
    int aW;                                                  // sigma_inv scatter base
    {
        int j = tid;
        #pragma unroll
        for (int c = 0; c < NQ; ++c) {
            int t = (c + 1) % NQ;
            int cb = (j >> (NQ - 1 - c)) & 1;
            j ^= cb << (NQ - 1 - t);
        }
        aW = wmix(j);
    }

    // ---- layers: 12 register gates, 3 LDS round trips, 3 barriers each ----
    #pragma unroll 1
    for (int l = 0; l < NL; ++l) {
        const int LB = l * NQ;

        APPLY4(LB, 8);                       // wires 8..11 on bits i3..i0
        #pragma unroll
        for (int k = 0; k < 4; ++k) {        // W1: 4x b128 (4 packed amps each)
            uint4 v;
            v.x = pkamp(av[4 * k]);     v.y = pkamp(av[4 * k + 1]);
            v.z = pkamp(av[4 * k + 2]); v.w = pkamp(av[4 * k + 3]);
            *(uint4*)&sh[a1 ^ wmix(4 * k)] = v;
        }
        __syncthreads();

        #pragma unroll
        for (int r = 0; r < APT; ++r)        // R2: own bits i7..i4 (b32, 2-way)
            av[r] = unpkamp(sh[a2 ^ wmix(r << 4)]);
        APPLY4(LB, 4);                       // wires 4..7
        #pragma unroll
        for (int r = 0; r < APT; ++r)        // W2: same addresses as R2
            sh[a2 ^ wmix(r << 4)] = pkamp(av[r]);
        __syncthreads();

        #pragma unroll
        for (int r = 0; r < APT; ++r)        // R3: own bits i11..i8 (b32, 2-way)
            av[r] = unpkamp(sh[a3 ^ wmix(r << 8)]);
        APPLY4(LB, 0);                       // wires 0..3
        #pragma unroll
        for (int r = 0; r < APT; ++r)        // W3σ: scatter through sigma_inv
            sh[aW ^ wmix(sigma_inv_c(r << 8))] = pkamp(av[r]);
        __syncthreads();

        #pragma unroll
        for (int k = 0; k < 4; ++k) {        // R1': 4x b128, own O1 region
            const uint4 v = *(const uint4*)&sh[a1 ^ wmix(4 * k)];
            av[4 * k]     = unpkamp(v.x);
            av[4 * k + 1] = unpkamp(v.y);
            av[4 * k + 2] = unpkamp(v.z);
            av[4 * k + 3] = unpkamp(v.w);
        }
        // no barrier: next W1 rewrites only this thread's own just-read slots
    }

    // ---- Z expectations (state in O1 ownership, fp32 registers) ----
    float S = 0.f, a8 = 0.f, a9 = 0.f, a10 = 0.f, a11 = 0.f;
    #pragma unroll
    for (int r = 0; r < APT; ++r) {
        const float pr = av[r].x * av[r].x + av[r].y * av[r].y;
        S += pr;
        a8  += (r & 8) ? -pr : pr;
        a9  += (r & 4) ? -pr : pr;
        a10 += (r & 2) ? -pr : pr;
        a11 += (r & 1) ? -pr : pr;
    }
    float vals[NQ];
    #pragma unroll
    for (int w = 0; w < 8; ++w)
        vals[w] = ((tid >> (7 - w)) & 1) ? -S : S;
    vals[8] = a8; vals[9] = a9; vals[10] = a10; vals[11] = a11;
    #pragma unroll
    for (int m = 1; m <= 32; m <<= 1) {
        #pragma unroll
        for (int w = 0; w < NQ; ++w) vals[w] += __shfl_xor(vals[w], m);
    }
    __syncthreads();   // all waves done with sh before red alias is written
    if (lane == 0) {
        #pragma unroll
        for (int w = 0; w < NQ; ++w) red[wv * NQ + w] = vals[w];
    }
    __syncthreads();
    if (tid < NQ)
        red[48 + tid] = red[tid] + red[NQ + tid] + red[2 * NQ + tid] + red[3 * NQ + tid];
    __syncthreads();
    if (tid < NQ) {
        float v = db[tid];
        #pragma unroll
        for (int w = 0; w < NQ; ++w) v += red[48 + w] * dw[w * NQ + tid];
        out[s * NQ + tid] = tanhf(v);
    }
}

extern "C" void kernel_launch(void* const* d_in, const int* in_sizes, int n_in,
                              void* d_out, int out_size, void* d_ws, size_t ws_size,
                              hipStream_t stream) {
    const float* x  = (const float*)d_in[0];
    const float* qw = (const float*)d_in[1];
    const float* dw = (const float*)d_in[2];
    const float* db = (const float*)d_in[3];
    float* out   = (float*)d_out;
    float* gates = (float*)d_ws;            // 48*16 floats = 3072 B
    int batch = in_sizes[0] / NQ;
    gate_kernel<<<1, 64, 0, stream>>>(qw, gates);
    qsim_kernel<<<batch, BLK, 0, stream>>>(x, gates, dw, db, out);
}

// Round 13
// 182.207 us; speedup vs baseline: 1.0091x; 1.0091x over previous
//
#include <hip/hip_runtime.h>
#include <math.h>

#define NQ   12
#define NL   4
#define DIM  4096          // 2^NQ
#define BLK  256
#define APT  16            // amplitudes per thread

typedef float v2f __attribute__((ext_vector_type(2)));

// Word address of amplitude i's real part (imag at +1). Interleaved re/im,
// XOR bank swizzle f(i) = (i>>4 ^ i>>8)&7 into word bits 2..4 (keeps 16B align).
// GF(2)-linear for disjoint-bit arguments. Conflict-free measured (r10: 0).
__device__ __forceinline__ constexpr int wmix(int i) {
    return (i << 1) ^ ((((i >> 4) ^ (i >> 8)) & 7) << 2);
}

// Inverse CNOT-ring map (CNOTs are involutions; apply in forward order) — for
// the sigma-folded scatter: store pre[i] at slot sigma_inv(i).
__device__ __forceinline__ constexpr int sigma_inv_c(int i) {
    int j = i;
    for (int c = 0; c < NQ; ++c) {
        int t = (c + 1) % NQ;
        int cb = (j >> (NQ - 1 - c)) & 1;
        j ^= cb << (NQ - 1 - t);
    }
    return j;
}

// Packed-complex gate update: N0 = u00*A0 + u01*A1, N1 = u10*A0 + u11*A1.
// Gate table stores real coeffs as {ur,ur} and imag coeffs as {-ui,+ui}, so
// the shuffled term is a PURE half-swap (no negate) -> folds to op_sel:[1,0].
#define CGATE(AV, R0, R1)                                            \
  { const v2f A0 = AV[R0], A1 = AV[R1];                              \
    const v2f A0s = __builtin_shufflevector(A0, A0, 1, 0);           \
    const v2f A1s = __builtin_shufflevector(A1, A1, 1, 0);           \
    v2f N0 = b00r * A0;                                              \
    N0 = __builtin_elementwise_fma(b00i, A0s, N0);                   \
    N0 = __builtin_elementwise_fma(b01r, A1,  N0);                   \
    N0 = __builtin_elementwise_fma(b01i, A1s, N0);                   \
    v2f N1 = b10r * A0;                                              \
    N1 = __builtin_elementwise_fma(b10i, A0s, N1);                   \
    N1 = __builtin_elementwise_fma(b11r, A1,  N1);                   \
    N1 = __builtin_elementwise_fma(b11i, A1s, N1);                   \
    AV[R0] = N0; AV[R1] = N1; }

// 4 gates on register-index bits 3..0; bit j <-> wire WB+3-j. Gate coeffs are
// wave-uniform global loads (scalar path).
#define APPLY4(LB, WB)                                               \
  { _Pragma("unroll")                                                \
    for (int j = 0; j < 4; ++j) {                                    \
      const int gb = ((LB) + (WB) + 3 - j) * 8;                      \
      const v2f b00r = gg[gb + 0], b00i = gg[gb + 1];                \
      const v2f b01r = gg[gb + 2], b01i = gg[gb + 3];                \
      const v2f b10r = gg[gb + 4], b10i = gg[gb + 5];                \
      const v2f b11r = gg[gb + 6], b11i = gg[gb + 7];                \
      _Pragma("unroll")                                              \
      for (int h = 0; h < 8; ++h) {                                  \
        const int r0 = ((h >> j) << (j + 1)) | (h & ((1 << j) - 1)); \
        CGATE(av, r0, r0 | (1 << j));                                \
      }                                                              \
    } }

// ---- pre-kernel: fuse RZ*RY*RX into d_ws ----
// Per gate 16 floats: entry k (u00,u01,u10,u11): [4k]={ur,ur}, [4k+2]={-ui,+ui}.
__global__ __launch_bounds__(64) void gate_kernel(
    const float* __restrict__ qw, float* __restrict__ gout)
{
    const int t = threadIdx.x;
    if (t < NL * NQ) {
        const int p = (t / NQ) * 3 * NQ + 3 * (t % NQ);
        float t1 = qw[p], t2 = qw[p + 1], t3 = qw[p + 2];
        float a, b, c, d, gr, h;
        sincosf(0.5f * t1, &b, &a);   // RX
        sincosf(0.5f * t2, &d, &c);   // RY
        sincosf(0.5f * t3, &h, &gr);  // RZ
        float m00r =  c * a, m00i =  d * b;
        float m01r = -d * a, m01i = -c * b;
        float m10r =  d * a, m10i = -c * b;
        float m11r =  c * a, m11i = -d * b;
        float G[8];
        G[0] = gr * m00r + h * m00i;  G[1] = gr * m00i - h * m00r;
        G[2] = gr * m01r + h * m01i;  G[3] = gr * m01i - h * m01r;
        G[4] = gr * m10r - h * m10i;  G[5] = gr * m10i + h * m10r;
        G[6] = gr * m11r - h * m11i;  G[7] = gr * m11i + h * m11r;
        #pragma unroll
        for (int k = 0; k < 4; ++k) {
            gout[t * 16 + 4 * k + 0] =  G[2 * k];
            gout[t * 16 + 4 * k + 1] =  G[2 * k];
            gout[t * 16 + 4 * k + 2] = -G[2 * k + 1];
            gout[t * 16 + 4 * k + 3] =  G[2 * k + 1];
        }
    }
}

__global__ __launch_bounds__(BLK) void qsim_kernel(
    const float* __restrict__ x,      // (B, 12)
    const float* __restrict__ gates,  // (48*16,) arranged gate matrices (d_ws)
    const float* __restrict__ dw,     // (12, 12)
    const float* __restrict__ db,     // (12,)
    float* __restrict__ out)          // (B, 12)
{
    __shared__ __align__(16) float sh[2 * DIM];   // 32768 B (5 blocks/CU)
    float* xv    = sh;        // aliases, dead once state staged
    float* enc_c = sh + 16;
    float* enc_s = sh + 32;
    float* red   = sh;        // reused after final barrier

    const int tid  = threadIdx.x;
    const int lane = tid & 63;
    const int wv   = tid >> 6;
    const int s    = blockIdx.x;
    const v2f* __restrict__ gg = (const v2f*)gates;

    if (tid < NQ) xv[tid] = x[s * NQ + tid];
    __syncthreads();
    if (tid < NQ) {
        float ss = 0.f;
        #pragma unroll
        for (int j = 0; j < NQ; ++j) ss += xv[j] * xv[j];
        float inv = rsqrtf(fmaxf(ss, 1e-12f));
        float mx = 0.f;
        #pragma unroll
        for (int j = 0; j < NQ; ++j) mx = fmaxf(mx, fabsf(xv[j] * inv));
        float ang = 3.14159265358979323846f * (xv[tid] * inv) / (mx + 1e-8f);
        float cc, sn;
        sincosf(0.5f * ang, &sn, &cc);
        enc_c[tid] = cc; enc_s[tid] = sn;
    }
    __syncthreads();

    // ---- product-state init in registers (O1: i = (tid<<4)|r) ----
    v2f av[APT];
    {
        float prefix = 1.f;
        #pragma unroll
        for (int w = 0; w < 8; ++w)
            prefix *= ((tid >> (7 - w)) & 1) ? enc_s[w] : enc_c[w];
        float u4[4], v4[4];
        #pragma unroll
        for (int k = 0; k < 4; ++k) {
            u4[k] = ((k & 2) ? enc_s[8]  : enc_c[8])  * ((k & 1) ? enc_s[9]  : enc_c[9]);
            v4[k] = ((k & 2) ? enc_s[10] : enc_c[10]) * ((k & 1) ? enc_s[11] : enc_c[11]);
        }
        #pragma unroll
        for (int r = 0; r < APT; ++r)
            av[r] = (v2f){ prefix * u4[r >> 2] * v4[r & 3], 0.f };
    }
    __syncthreads();   // enc reads done before W1 overwrites the alias region

    // Address bases (per-r offsets are compile-time XORs; maps GF(2)-linear).
    const int a1 = wmix(tid << 4);                           // O1 (W1, R1')
    const int a2 = wmix(((tid & 0xF0) << 4) | (tid & 0x0F)); // O2: i=th<<8|r<<4|tl
    const int a3 = wmix(tid);                                // O3: i=(r<<8)|tid
    int aW;                                                  // sigma_inv scatter base
    {
        int j = tid;
        #pragma unroll
        for (int c = 0; c < NQ; ++c) {
            int t = (c + 1) % NQ;
            int cb = (j >> (NQ - 1 - c)) & 1;
            j ^= cb << (NQ - 1 - t);
        }
        aW = wmix(j);
    }

    // ---- layers: 12 register gates, 3 LDS round trips, 2 block barriers ----
    #pragma unroll 1
    for (int l = 0; l < NL; ++l) {
        const int LB = l * NQ;

        APPLY4(LB, 8);                       // wires 8..11 on bits i3..i0
        #pragma unroll
        for (int k = 0; k < 8; ++k)          // W1: b128 to own O1 region
            *(float4*)&sh[a1 ^ wmix(2 * k)] =
                make_float4(av[2 * k].x, av[2 * k].y, av[2 * k + 1].x, av[2 * k + 1].y);
        // O1->O2 is WAVE-INTERNAL: R2's reader T pulls amps whose W1-writers
        // are threads (T&0xF0)|m — same 64-lane wave (bits 6-7 preserved).
        // Only DS-completion visibility needed, not a block barrier.
        asm volatile("s_waitcnt lgkmcnt(0)" ::: "memory");

        #pragma unroll
        for (int r = 0; r < APT; ++r)        // R2: own bits i7..i4
            av[r] = *(const v2f*)&sh[a2 ^ wmix(r << 4)];
        APPLY4(LB, 4);                       // wires 4..7
        #pragma unroll
        for (int r = 0; r < APT; ++r)        // W2: same addresses as R2 (own RMW)
            *(v2f*)&sh[a2 ^ wmix(r << 4)] = av[r];
        __syncthreads();                     // R3 reads cross-wave W2 data

        #pragma unroll
        for (int r = 0; r < APT; ++r)        // R3: own bits i11..i8
            av[r] = *(const v2f*)&sh[a3 ^ wmix(r << 8)];
        APPLY4(LB, 0);                       // wires 0..3
        #pragma unroll
        for (int r = 0; r < APT; ++r)        // W3σ: scatter through sigma_inv
            *(v2f*)&sh[aW ^ wmix(sigma_inv_c(r << 8))] = av[r];
        __syncthreads();                     // R1' reads cross-wave W3σ data

        #pragma unroll
        for (int k = 0; k < 8; ++k) {        // R1': contiguous b128, own O1 region
            const float4 v = *(const float4*)&sh[a1 ^ wmix(2 * k)];
            av[2 * k]     = (v2f){ v.x, v.y };
            av[2 * k + 1] = (v2f){ v.z, v.w };
        }
        // no barrier: next W1 rewrites only this thread's own just-read slots
    }

    // ---- Z expectations (state in O1 ownership) ----
    float S = 0.f, a8 = 0.f, a9 = 0.f, a10 = 0.f, a11 = 0.f;
    #pragma unroll
    for (int r = 0; r < APT; ++r) {
        const float pr = av[r].x * av[r].x + av[r].y * av[r].y;
        S += pr;
        a8  += (r & 8) ? -pr : pr;
        a9  += (r & 4) ? -pr : pr;
        a10 += (r & 2) ? -pr : pr;
        a11 += (r & 1) ? -pr : pr;
    }
    float vals[NQ];
    #pragma unroll
    for (int w = 0; w < 8; ++w)
        vals[w] = ((tid >> (7 - w)) & 1) ? -S : S;
    vals[8] = a8; vals[9] = a9; vals[10] = a10; vals[11] = a11;
    #pragma unroll
    for (int m = 1; m <= 32; m <<= 1) {
        #pragma unroll
        for (int w = 0; w < NQ; ++w) vals[w] += __shfl_xor(vals[w], m);
    }
    __syncthreads();   // all waves done with sh before red alias is written
    if (lane == 0) {
        #pragma unroll
        for (int w = 0; w < NQ; ++w) red[wv * NQ + w] = vals[w];
    }
    __syncthreads();
    if (tid < NQ)
        red[48 + tid] = red[tid] + red[NQ + tid] + red[2 * NQ + tid] + red[3 * NQ + tid];
    __syncthreads();
    if (tid < NQ) {
        float v = db[tid];
        #pragma unroll
        for (int w = 0; w < NQ; ++w) v += red[48 + w] * dw[w * NQ + tid];
        out[s * NQ + tid] = tanhf(v);
    }
}

extern "C" void kernel_launch(void* const* d_in, const int* in_sizes, int n_in,
                              void* d_out, int out_size, void* d_ws, size_t ws_size,
                              hipStream_t stream) {
    const float* x  = (const float*)d_in[0];
    const float* qw = (const float*)d_in[1];
    const float* dw = (const float*)d_in[2];
    const float* db = (const float*)d_in[3];
    float* out   = (float*)d_out;
    float* gates = (float*)d_ws;            // 48*16 floats = 3072 B
    int batch = in_sizes[0] / NQ;
    gate_kernel<<<1, 64, 0, stream>>>(qw, gates);
    qsim_kernel<<<batch, BLK, 0, stream>>>(x, gates, dw, db, out);
}

// Round 14
// 152.408 us; speedup vs baseline: 1.2064x; 1.1955x over previous
//
#include <hip/hip_runtime.h>
#include <math.h>

#define NQ   12
#define NL   4
#define BLK  256

typedef float v4f  __attribute__((ext_vector_type(4)));
typedef __fp16 v8h __attribute__((ext_vector_type(8)));

// Inverse CNOT-ring map (apply CNOTs in forward order). GF(2)-linear.
// final[i] = preC[sigma(i)]  =>  store preC[j] at slot sigma_inv(j).
__device__ __forceinline__ constexpr int sigma_inv_c(int i) {
    int j = i;
    for (int c = 0; c < NQ; ++c) {
        int t = (c + 1) % NQ;
        int cb = (j >> (NQ - 1 - c)) & 1;
        j ^= cb << (NQ - 1 - t);
    }
    return j;
}

// LDS halfword address of (part p, column CC(8b), row r(4b)) in one 16KB buffer.
// line(10b) = p<<9 | CC<<1 | r>>3, swizzle: bits 2..0 ^= bits 8..6; hw = r&7.
// Swizzle keeps all b128/b64 runs intact (they vary r&7 only) and spreads
// bank groups uniformly for both the col-reads and the row-writes.
__device__ __forceinline__ int haddr(int p, int CC, int r) {
    int line = (p << 9) | (CC << 1) | (r >> 3);
    line ^= (line >> 6) & 7;
    return line * 8 + (r & 7);
}

__device__ __forceinline__ unsigned pk2(float a, float b) {
    return __builtin_bit_cast(unsigned, __builtin_amdgcn_cvt_pkrtz(a, b));
}

// ---- pre-kernel: fused gates -> 12 U16 matrices -> f16 B-fragments in d_ws ----
// Per (layer,phase): B1 = [Ur^T ; -Ui^T], B2 = [Ui^T ; Ur^T]  (32x16 f16 each),
// stored in mfma B-fragment lane order: value B[k][n] at hw ((k>>3)*16+n)*8+(k&7).
__device__ __forceinline__ int fslot(int k, int n) {
    return ((k >> 3) * 16 + n) * 8 + (k & 7);
}

__global__ __launch_bounds__(BLK) void gate_kernel(
    const float* __restrict__ qw, __fp16* __restrict__ gout)
{
    __shared__ float G[NL * NQ][8];   // fused RZ*RY*RX, {00r,00i,01r,01i,10r,10i,11r,11i}
    const int t = threadIdx.x;
    if (t < NL * NQ) {
        const int p = (t / NQ) * 3 * NQ + 3 * (t % NQ);
        float t1 = qw[p], t2 = qw[p + 1], t3 = qw[p + 2];
        float a, b, c, d, gr, h;
        sincosf(0.5f * t1, &b, &a);   // RX
        sincosf(0.5f * t2, &d, &c);   // RY
        sincosf(0.5f * t3, &h, &gr);  // RZ
        float m00r =  c * a, m00i =  d * b;
        float m01r = -d * a, m01i = -c * b;
        float m10r =  d * a, m10i = -c * b;
        float m11r =  c * a, m11i = -d * b;
        float* g = G[t];
        g[0] = gr * m00r + h * m00i;  g[1] = gr * m00i - h * m00r;
        g[2] = gr * m01r + h * m01i;  g[3] = gr * m01i - h * m01r;
        g[4] = gr * m10r - h * m10i;  g[5] = gr * m10i + h * m10r;
        g[6] = gr * m11r - h * m11i;  g[7] = gr * m11i + h * m11r;
    }
    __syncthreads();
    const int n = t & 15, r = t >> 4;
    for (int mat = 0; mat < 12; ++mat) {
        const int layer = mat / 3, ph = mat % 3;
        const int wbase = (ph == 0) ? 8 : (ph == 1) ? 4 : 0;  // rows: A=i3..0(w8-11), B=i7..4(w4-7), C=i11..8(w0-3)
        float cr = 1.f, ci = 0.f;
        #pragma unroll
        for (int b = 0; b < 4; ++b) {         // bit (3-b) of row <-> wire wbase+b
            const float* g = G[layer * NQ + wbase + b];
            const int rb = (r >> (3 - b)) & 1, nb = (n >> (3 - b)) & 1;
            const float er = g[(nb * 2 + rb) * 2], ei = g[(nb * 2 + rb) * 2 + 1];
            const float xr = cr * er - ci * ei, xi = cr * ei + ci * er;
            cr = xr; ci = xi;
        }
        __fp16* b1 = gout + (mat * 2 + 0) * 512;
        __fp16* b2 = gout + (mat * 2 + 1) * 512;
        b1[fslot(r, n)]      = (__fp16)cr;
        b1[fslot(16 + r, n)] = (__fp16)(-ci);
        b2[fslot(r, n)]      = (__fp16)ci;
        b2[fslot(16 + r, n)] = (__fp16)cr;
    }
}

// Reads: state-as-A fragments for the current phase from buffer SRC.
#define READ_FRAGS(SRC)                                                     \
    _Pragma("unroll")                                                       \
    for (int q = 0; q < 4; ++q)                                             \
        af[q] = __builtin_bit_cast(v8h, *(const uint4*)&sh[(SRC) +          \
                    haddr(p, (wv << 6) | (q << 4) | nn, (g & 1) * 8)]);

#define MFMA_PHASE(MAT)                                                     \
    { const v8h b1 = gf[((MAT) * 2 + 0) * 64 + lane];                       \
      const v8h b2 = gf[((MAT) * 2 + 1) * 64 + lane];                       \
      _Pragma("unroll")                                                     \
      for (int q = 0; q < 4; ++q) {                                         \
          d1[q] = __builtin_amdgcn_mfma_f32_16x16x32_f16(af[q], b1, zf, 0, 0, 0); \
          d2[q] = __builtin_amdgcn_mfma_f32_16x16x32_f16(af[q], b2, zf, 0, 0, 0); \
      } }

// D (rows n=lane&15 of out, cols m=4g+reg) -> next phase container at DST.
// Next-phase coords: row' = 4g+reg (consecutive hw, one b64), col' = nn<<4|wv<<2|q.
#define WRITE_COLS(DST)                                                     \
    _Pragma("unroll")                                                       \
    for (int q = 0; q < 4; ++q) {                                           \
        const int CCn = (nn << 4) | (wv << 2) | q;                          \
        *(uint2*)&sh[(DST) + haddr(0, CCn, 4 * g)] =                        \
            make_uint2(pk2(d1[q].x, d1[q].y), pk2(d1[q].z, d1[q].w));       \
        *(uint2*)&sh[(DST) + haddr(1, CCn, 4 * g)] =                        \
            make_uint2(pk2(d2[q].x, d2[q].y), pk2(d2[q].z, d2[q].w));       \
    }

// Phase-C out -> phase-A container with the CNOT-ring permutation folded in:
// amp j -> slot i = sigma_inv(j); b16 scatter (sigma's cascade breaks runs).
#define WRITE_SIGMA(DST)                                                    \
    _Pragma("unroll")                                                       \
    for (int q = 0; q < 4; ++q) {                                           \
        const int iq = ifix ^ sigma_inv_c(q << 4);                          \
        _Pragma("unroll")                                                   \
        for (int rg = 0; rg < 4; ++rg) {                                    \
            const int ii = iq ^ sigma_inv_c(rg);                            \
            sh[(DST) + haddr(0, ii >> 4, ii & 15)] = (__fp16)d1[q][rg];     \
            sh[(DST) + haddr(1, ii >> 4, ii & 15)] = (__fp16)d2[q][rg];     \
        }                                                                   \
    }

__global__ __launch_bounds__(BLK) void qsim_kernel(
    const float* __restrict__ x,      // (B, 12)
    const __fp16* __restrict__ gates, // 12 x (B1,B2) f16 fragment tables (d_ws)
    const float* __restrict__ dw,     // (12, 12)
    const float* __restrict__ db,     // (12,)
    float* __restrict__ out)          // (B, 12)
{
    __shared__ __align__(16) __fp16 sh[16384];   // two 16KB ping-pong buffers
    float* xv    = (float*)sh;
    float* enc_c = (float*)sh + 16;
    float* enc_s = (float*)sh + 32;
    float* red   = (float*)sh;

    const int tid  = threadIdx.x;
    const int lane = tid & 63;
    const int wv   = tid >> 6;
    const int s    = blockIdx.x;
    const int nn = lane & 15, g = lane >> 4, p = g >> 1;
    const v8h* gf = (const v8h*)gates;
    const v4f zf = {0.f, 0.f, 0.f, 0.f};

    if (tid < NQ) xv[tid] = x[s * NQ + tid];
    __syncthreads();
    if (tid < NQ) {
        float ss = 0.f;
        #pragma unroll
        for (int j = 0; j < NQ; ++j) ss += xv[j] * xv[j];
        float inv = rsqrtf(fmaxf(ss, 1e-12f));
        float mx = 0.f;
        #pragma unroll
        for (int j = 0; j < NQ; ++j) mx = fmaxf(mx, fabsf(xv[j] * inv));
        float ang = 3.14159265358979323846f * (xv[tid] * inv) / (mx + 1e-8f);
        float cc, sn;
        sincosf(0.5f * ang, &sn, &cc);
        enc_c[tid] = cc; enc_s[tid] = sn;
    }
    __syncthreads();

    // ---- product-state init directly as phase-A A-fragments ----
    // A[m=nn][k=g*8+j]: k<16 = re(row k), k>=16 = im (zero at init).
    v8h af[4];
    {
        #define PICK(W, B) ((B) ? enc_s[W] : enc_c[W])
        if (g < 2) {
            float R[8];
            #pragma unroll
            for (int j = 0; j < 8; ++j) {
                const int r = g * 8 + j;           // row (i3..0), wires 8..11
                R[j] = PICK(8, (r >> 3) & 1) * PICK(9, (r >> 2) & 1)
                     * PICK(10, (r >> 1) & 1) * PICK(11, r & 1);
            }
            const float Pfix = PICK(0, (wv >> 1) & 1) * PICK(1, wv & 1)
                             * PICK(4, (nn >> 3) & 1) * PICK(5, (nn >> 2) & 1)
                             * PICK(6, (nn >> 1) & 1) * PICK(7, nn & 1);
            #pragma unroll
            for (int q = 0; q < 4; ++q) {
                const float Pq = Pfix * PICK(2, (q >> 1) & 1) * PICK(3, q & 1);
                #pragma unroll
                for (int j = 0; j < 8; ++j) af[q][j] = (__fp16)(Pq * R[j]);
            }
        } else {
            const uint4 uz = {0u, 0u, 0u, 0u};
            #pragma unroll
            for (int q = 0; q < 4; ++q) af[q] = __builtin_bit_cast(v8h, uz);
        }
        #undef PICK
    }
    __syncthreads();   // enc reads done before buffer 0 is overwritten

    const int ifix = sigma_inv_c((nn << 8) | (wv << 6) | (g << 2));

    v4f d1[4], d2[4];
    #pragma unroll 1
    for (int l = 0; l < NL; ++l) {
        const int XA = (l & 1) * 8192;    // A->B target; also sigma target
        const int XB = 8192 - XA;         // B->C target; also phase-A source

        if (l > 0) { READ_FRAGS(XB) }     // layer 0 phase A uses init frags
        MFMA_PHASE(l * 3 + 0)             // wires 8..11
        WRITE_COLS(XA)
        __syncthreads();

        READ_FRAGS(XA)
        MFMA_PHASE(l * 3 + 1)             // wires 4..7
        WRITE_COLS(XB)
        __syncthreads();

        READ_FRAGS(XB)
        MFMA_PHASE(l * 3 + 2)             // wires 0..3
        if (l < NL - 1) {
            WRITE_SIGMA(XA)
            __syncthreads();
        }
    }

    // ---- Z expectations straight from final D-regs (sigma applied via index) ----
    float vals[NQ];
    #pragma unroll
    for (int w = 0; w < NQ; ++w) vals[w] = 0.f;
    #pragma unroll
    for (int q = 0; q < 4; ++q) {
        const int iq = ifix ^ sigma_inv_c(q << 4);
        #pragma unroll
        for (int rg = 0; rg < 4; ++rg) {
            const int ii = iq ^ sigma_inv_c(rg);
            const float pr = d1[q][rg] * d1[q][rg] + d2[q][rg] * d2[q][rg];
            #pragma unroll
            for (int w = 0; w < NQ; ++w)
                vals[w] += ((ii >> (11 - w)) & 1) ? -pr : pr;
        }
    }
    #pragma unroll
    for (int m = 1; m <= 32; m <<= 1) {
        #pragma unroll
        for (int w = 0; w < NQ; ++w) vals[w] += __shfl_xor(vals[w], m);
    }
    __syncthreads();   // all waves done with sh before red alias is written
    if (lane == 0) {
        #pragma unroll
        for (int w = 0; w < NQ; ++w) red[wv * NQ + w] = vals[w];
    }
    __syncthreads();
    if (tid < NQ)
        red[48 + tid] = red[tid] + red[NQ + tid] + red[2 * NQ + tid] + red[3 * NQ + tid];
    __syncthreads();
    if (tid < NQ) {
        float v = db[tid];
        #pragma unroll
        for (int w = 0; w < NQ; ++w) v += red[48 + w] * dw[w * NQ + tid];
        out[s * NQ + tid] = tanhf(v);
    }
}

extern "C" void kernel_launch(void* const* d_in, const int* in_sizes, int n_in,
                              void* d_out, int out_size, void* d_ws, size_t ws_size,
                              hipStream_t stream) {
    const float* x  = (const float*)d_in[0];
    const float* qw = (const float*)d_in[1];
    const float* dw = (const float*)d_in[2];
    const float* db = (const float*)d_in[3];
    float* out = (float*)d_out;
    __fp16* gates = (__fp16*)d_ws;          // 12 x 2 x 512 f16 = 24576 B
    int batch = in_sizes[0] / NQ;
    gate_kernel<<<1, BLK, 0, stream>>>(qw, gates);
    qsim_kernel<<<batch, BLK, 0, stream>>>(x, gates, dw, db, out);
}